// Round 1
// baseline (2210.578 us; speedup 1.0000x reference)
//
#include <hip/hip_runtime.h>
#include <hip/hip_bf16.h>
#include <math.h>

// Problem constants (from reference): B=2, T=2048, C=1024, H=16, Dh=64
#define BATCH 2
#define SEQ   2048
#define DMODEL 1024
#define NHEADS 16
#define HDIM  64
#define MROWS (BATCH*SEQ)   // 4096

// ---------------- GEMM: Y = A @ W^T + bias ----------------
// A: [M, K] row-major, W: [N, K] row-major (torch Linear [out,in]).
// REMAP=true  -> scatter Y into [B, H, T, Dh] layout (for Q/K/V)
// REMAP=false -> linear Y [M, N] (for final output)
#define TM 64
#define TN 64
#define TK 16

template<bool REMAP>
__global__ __launch_bounds__(256) void gemm_bias_kernel(
    const float* __restrict__ A, const float* __restrict__ W,
    const float* __restrict__ bias, float* __restrict__ Y,
    int M, int N, int K)
{
    __shared__ float As[TM][TK + 1];
    __shared__ float Bs[TN][TK + 1];

    const int tid = threadIdx.x;
    const int tx = tid & 15;        // 0..15 -> output cols
    const int ty = tid >> 4;        // 0..15 -> output rows
    const int m0 = blockIdx.y * TM;
    const int n0 = blockIdx.x * TN;

    float acc[4][4] = {};

    const int lk = tid & 15;        // k within tile
    const int lr = tid >> 4;        // row (16 rows per pass)

    for (int k0 = 0; k0 < K; k0 += TK) {
        #pragma unroll
        for (int p = 0; p < 4; ++p) {
            int r = lr + p * 16;
            As[r][lk] = A[(size_t)(m0 + r) * K + k0 + lk];
            Bs[r][lk] = W[(size_t)(n0 + r) * K + k0 + lk];
        }
        __syncthreads();
        #pragma unroll
        for (int kk = 0; kk < TK; ++kk) {
            float a[4], b[4];
            #pragma unroll
            for (int i = 0; i < 4; ++i) a[i] = As[ty * 4 + i][kk];
            #pragma unroll
            for (int j = 0; j < 4; ++j) b[j] = Bs[tx * 4 + j][kk];
            #pragma unroll
            for (int i = 0; i < 4; ++i)
                #pragma unroll
                for (int j = 0; j < 4; ++j)
                    acc[i][j] += a[i] * b[j];
        }
        __syncthreads();
    }

    #pragma unroll
    for (int i = 0; i < 4; ++i) {
        int row = m0 + ty * 4 + i;
        #pragma unroll
        for (int j = 0; j < 4; ++j) {
            int col = n0 + tx * 4 + j;
            float v = acc[i][j] + bias[col];
            if (REMAP) {
                int b = row / SEQ, t = row % SEQ;
                int h = col / HDIM, d = col % HDIM;
                Y[(((size_t)b * NHEADS + h) * SEQ + t) * HDIM + d] = v;
            } else {
                Y[(size_t)row * N + col] = v;
            }
        }
    }
}

// ---------------- Flash attention (causal) ----------------
// Q,K,V: [B, H, T, Dh] fp32.  O: [B, T, C] fp32.
// One block: one (b,h), BQ=32 query rows; loop over BK=64 key rows.
#define BQ 32
#define BK 64

__global__ __launch_bounds__(256) void attn_kernel(
    const float* __restrict__ Q, const float* __restrict__ K,
    const float* __restrict__ V, float* __restrict__ O)
{
    __shared__ float Qs[BQ][HDIM + 1];
    __shared__ float Ks[BK][HDIM + 1];
    __shared__ float Vs[BK][HDIM + 1];
    __shared__ float Ps[BQ][BK + 1];
    __shared__ float mrow[BQ], lrow[BQ], srow[BQ];

    const int tid = threadIdx.x;
    const int bh = blockIdx.y;              // b*H + h
    const int b = bh >> 4, h = bh & 15;
    const int q0 = blockIdx.x * BQ;

    const float* Qbase = Q + ((size_t)bh * SEQ + q0) * HDIM;
    const float* Kbase = K + (size_t)bh * SEQ * HDIM;
    const float* Vbase = V + (size_t)bh * SEQ * HDIM;

    // load Q tile (2048 floats, 8/thread)
    for (int i = tid; i < BQ * HDIM; i += 256)
        Qs[i / HDIM][i % HDIM] = Qbase[i];
    if (tid < BQ) { mrow[tid] = -INFINITY; lrow[tid] = 0.f; }

    const int r  = tid >> 3;           // query row 0..31 (score phase)
    const int cg = tid & 7;            // col group 0..7 (8 k each)
    const int d0 = (tid & 7) * 8;      // PV phase: 8 output dims

    float o[8] = {};
    __syncthreads();

    const int ktiles = (q0 + BQ + BK - 1) / BK;  // tiles covering k <= q0+BQ-1
    for (int kt = 0; kt < ktiles; ++kt) {
        const int k0 = kt * BK;
        // load K,V tiles (4096 floats each, 16/thread)
        for (int i = tid; i < BK * HDIM; i += 256) {
            int rr = i / HDIM, dd = i % HDIM;
            Ks[rr][dd] = Kbase[(size_t)(k0 + rr) * HDIM + dd];
            Vs[rr][dd] = Vbase[(size_t)(k0 + rr) * HDIM + dd];
        }
        __syncthreads();

        // scores: thread computes 8 scores along k for row r
        float p[8];
        float tmax = -INFINITY;
        #pragma unroll
        for (int j = 0; j < 8; ++j) {
            const int kk = cg * 8 + j;
            float s = 0.f;
            #pragma unroll
            for (int d = 0; d < HDIM; ++d) s += Qs[r][d] * Ks[kk][d];
            s *= 0.125f;                                 // 1/sqrt(64)
            if (k0 + kk > q0 + r) s = -INFINITY;         // causal mask
            p[j] = s;
            tmax = fmaxf(tmax, s);
        }
        #pragma unroll
        for (int off = 1; off < 8; off <<= 1)
            tmax = fmaxf(tmax, __shfl_xor(tmax, off));

        const float mold = mrow[r];
        const float mnew = fmaxf(mold, tmax);            // finite (diag always present)
        const float scl = expf(mold - mnew);             // 0 on first tile
        float lsum = 0.f;
        #pragma unroll
        for (int j = 0; j < 8; ++j) {
            float pv = expf(p[j] - mnew);                // masked -> 0
            Ps[r][cg * 8 + j] = pv;
            lsum += pv;
        }
        #pragma unroll
        for (int off = 1; off < 8; off <<= 1)
            lsum += __shfl_xor(lsum, off);
        if (cg == 0) {
            mrow[r] = mnew;
            lrow[r] = lrow[r] * scl + lsum;
            srow[r] = scl;
        }
        __syncthreads();

        // PV: thread owns O[r][d0..d0+7]
        const float sr = srow[r];
        #pragma unroll
        for (int j = 0; j < 8; ++j) o[j] *= sr;
        for (int kk = 0; kk < BK; ++kk) {
            const float pv = Ps[r][kk];
            #pragma unroll
            for (int j = 0; j < 8; ++j) o[j] += pv * Vs[kk][d0 + j];
        }
        __syncthreads();
    }

    const float inv = 1.f / lrow[r];
    float* Ob = O + (((size_t)b * SEQ) + q0 + r) * DMODEL + h * HDIM + d0;
    #pragma unroll
    for (int j = 0; j < 8; ++j) Ob[j] = o[j] * inv;
}

// ---------------- launch ----------------
extern "C" void kernel_launch(void* const* d_in, const int* in_sizes, int n_in,
                              void* d_out, int out_size, void* d_ws, size_t ws_size,
                              hipStream_t stream) {
    const float* x   = (const float*)d_in[0];
    const float* w_q = (const float*)d_in[1];
    const float* b_q = (const float*)d_in[2];
    const float* w_k = (const float*)d_in[3];
    const float* b_k = (const float*)d_in[4];
    const float* w_v = (const float*)d_in[5];
    const float* b_v = (const float*)d_in[6];
    const float* w_o = (const float*)d_in[7];
    const float* b_o = (const float*)d_in[8];
    float* out = (float*)d_out;

    // workspace: Q, K, V ([B,H,T,Dh]) + O ([B,T,C]) -> 4 x 16 MB = 64 MB
    const size_t NELT = (size_t)MROWS * DMODEL;  // 4,194,304
    float* Qw = (float*)d_ws;
    float* Kw = Qw + NELT;
    float* Vw = Kw + NELT;
    float* Ow = Vw + NELT;

    dim3 gGrid(DMODEL / TN, MROWS / TM);   // (16, 64)
    gemm_bias_kernel<true><<<gGrid, 256, 0, stream>>>(x, w_q, b_q, Qw, MROWS, DMODEL, DMODEL);
    gemm_bias_kernel<true><<<gGrid, 256, 0, stream>>>(x, w_k, b_k, Kw, MROWS, DMODEL, DMODEL);
    gemm_bias_kernel<true><<<gGrid, 256, 0, stream>>>(x, w_v, b_v, Vw, MROWS, DMODEL, DMODEL);

    dim3 aGrid(SEQ / BQ, BATCH * NHEADS); // (64, 32)
    attn_kernel<<<aGrid, 256, 0, stream>>>(Qw, Kw, Vw, Ow);

    gemm_bias_kernel<false><<<gGrid, 256, 0, stream>>>(Ow, w_o, b_o, out, MROWS, DMODEL, DMODEL);
}

// Round 3
// 408.976 us; speedup vs baseline: 5.4051x; 5.4051x over previous
//
#include <hip/hip_runtime.h>
#include <hip/hip_bf16.h>
#include <math.h>

#define BATCH 2
#define SEQ   2048
#define DMODEL 1024
#define NHEADS 16
#define HDIM  64
#define MROWS (BATCH*SEQ)   // 4096

typedef __attribute__((ext_vector_type(8))) short bfr8;   // 8 bf16 (4 VGPRs)
typedef __attribute__((ext_vector_type(4))) float f32x4;  // MFMA C/D

__device__ inline unsigned short f2bf(float f) {
    union { float f; unsigned u; } v; v.f = f;
    unsigned r = v.u + 0x7FFFu + ((v.u >> 16) & 1u);   // RNE
    return (unsigned short)(r >> 16);
}

// ---------------- cast fp32 -> bf16 ----------------
__global__ __launch_bounds__(256) void cast_bf16(const float* __restrict__ in,
                                                 unsigned short* __restrict__ out, int n) {
    int i = (blockIdx.x * 256 + threadIdx.x) * 4;
    const int stride = gridDim.x * 256 * 4;
    for (; i < n; i += stride) {
        float4 v = *(const float4*)(in + i);
        ushort4 o;
        o.x = f2bf(v.x); o.y = f2bf(v.y); o.z = f2bf(v.z); o.w = f2bf(v.w);
        *(ushort4*)(out + i) = o;
    }
}

// ---------------- bf16 MFMA GEMM: Y = A @ W^T + bias ----------------
// A: [4096,1024] bf16, W: [1024,1024] bf16 (N,K).  Tile 128x128, BK=32.
// mode 0: Y bf16 remap [B,H,T,64]   (Q, K)
// mode 1: Y bf16 remap [B,H,64,T]   (V transposed)
// mode 2: Y fp32 linear [4096,1024] (final out)
__global__ __launch_bounds__(256) void gemm_bf16(
    const unsigned short* __restrict__ A, const unsigned short* __restrict__ W,
    const float* __restrict__ bias, void* __restrict__ Y, int mode)
{
    // K-grouped LDS layout: [buf][kgroup(4)][row(128)][8] bf16.
    // One tile = 128 rows x 32 k = 512 granules of 16B; LDS dest linear in
    // (kg*128+row) which equals the staging index -> satisfies global_load_lds's
    // wave-uniform-base + lane*16 requirement.
    __shared__ __align__(16) unsigned short As[2][4][128][8];
    __shared__ __align__(16) unsigned short Bs[2][4][128][8];

    const int tid = threadIdx.x;
    const int l = tid & 63, w = tid >> 6;
    const int wr = w >> 1, wc = w & 1;        // 2x2 waves -> 64x64 quadrants
    const int m0 = blockIdx.y * 128, n0 = blockIdx.x * 128;
    const int r15 = l & 15, g = l >> 4;

    f32x4 acc[4][4] = {};

    auto stage = [&](int buf, int k0) {
        #pragma unroll
        for (int s = 0; s < 2; ++s) {         // 2*256 = 512 granules (FIX: was 4)
            int gi = s * 256 + tid;           // granule 0..511
            int row = gi & 127, kg = gi >> 7; // kg in [0,4)
            const unsigned short* ga = A + (size_t)(m0 + row) * 1024 + k0 + kg * 8;
            const unsigned short* gb = W + (size_t)(n0 + row) * 1024 + k0 + kg * 8;
            __builtin_amdgcn_global_load_lds((const __attribute__((address_space(1))) void*)ga,
                (__attribute__((address_space(3))) void*)&As[buf][kg][row][0], 16, 0, 0);
            __builtin_amdgcn_global_load_lds((const __attribute__((address_space(1))) void*)gb,
                (__attribute__((address_space(3))) void*)&Bs[buf][kg][row][0], 16, 0, 0);
        }
    };

    stage(0, 0);
    __syncthreads();

    for (int t = 0; t < 32; ++t) {
        const int buf = t & 1;
        if (t + 1 < 32) stage(buf ^ 1, (t + 1) * 32);
        bfr8 a[4], b[4];
        #pragma unroll
        for (int m = 0; m < 4; ++m)
            a[m] = *(const bfr8*)&As[buf][g][wr * 64 + m * 16 + r15][0];
        #pragma unroll
        for (int n = 0; n < 4; ++n)
            b[n] = *(const bfr8*)&Bs[buf][g][wc * 64 + n * 16 + r15][0];
        #pragma unroll
        for (int m = 0; m < 4; ++m)
            #pragma unroll
            for (int n = 0; n < 4; ++n)
                acc[m][n] = __builtin_amdgcn_mfma_f32_16x16x32_bf16(a[m], b[n], acc[m][n], 0, 0, 0);
        __syncthreads();
    }

    #pragma unroll
    for (int m = 0; m < 4; ++m) {
        const int rowb = m0 + wr * 64 + m * 16 + g * 4;
        #pragma unroll
        for (int n = 0; n < 4; ++n) {
            const int col = n0 + wc * 64 + n * 16 + r15;
            const float bc = bias[col];
            #pragma unroll
            for (int i = 0; i < 4; ++i) {
                const float v = acc[m][n][i] + bc;
                const int rr = rowb + i;
                if (mode == 2) {
                    ((float*)Y)[(size_t)rr * 1024 + col] = v;
                } else {
                    const int bb = rr >> 11, tt = rr & 2047;
                    const int hh = col >> 6, dd = col & 63;
                    if (mode == 0)
                        ((unsigned short*)Y)[(((size_t)bb * NHEADS + hh) * SEQ + tt) * HDIM + dd] = f2bf(v);
                    else
                        ((unsigned short*)Y)[(((size_t)bb * NHEADS + hh) * HDIM + dd) * SEQ + tt] = f2bf(v);
                }
            }
        }
    }
}

// ---------------- MFMA flash attention (causal) ----------------
// Q,K: [B,H,T,64] bf16; VT: [B,H,64,T] bf16; O: [B,T,1024] bf16.
// One wave per 16 query rows. kv tiles of 32 (two 16-col S chunks).
__global__ __launch_bounds__(64) void attn_mfma(
    const unsigned short* __restrict__ Q, const unsigned short* __restrict__ K,
    const unsigned short* __restrict__ VT, unsigned short* __restrict__ O)
{
    __shared__ __align__(16) unsigned short Ps[4][16][8];  // P in k-grouped A-frag layout

    const int l = threadIdx.x;
    const int r15 = l & 15, g = l >> 4;
    const int q0 = blockIdx.x * 16;
    const int bh = blockIdx.y;

    const unsigned short* Qb = Q + (size_t)bh * SEQ * HDIM;
    const unsigned short* Kb = K + (size_t)bh * SEQ * HDIM;
    const unsigned short* Vb = VT + (size_t)bh * HDIM * SEQ;

    bfr8 qf[2];
    #pragma unroll
    for (int h = 0; h < 2; ++h)
        qf[h] = *(const bfr8*)(Qb + (size_t)(q0 + r15) * HDIM + h * 32 + g * 8);

    f32x4 o[4] = {};            // 4 d-chunks of 16
    float mrow[4], lrow[4];
    #pragma unroll
    for (int i = 0; i < 4; ++i) { mrow[i] = -INFINITY; lrow[i] = 0.f; }

    const int ntiles = (q0 + 47) / 32;
    for (int kt = 0; kt < ntiles; ++kt) {
        const int kv0 = kt * 32;

        // S = Q @ K^T (scaled), C-layout: row=q-off=(g*4+i), col=kv-off=r15 (+16*c)
        f32x4 s[2];
        #pragma unroll
        for (int c = 0; c < 2; ++c) {
            bfr8 kf0 = *(const bfr8*)(Kb + (size_t)(kv0 + c * 16 + r15) * HDIM + g * 8);
            bfr8 kf1 = *(const bfr8*)(Kb + (size_t)(kv0 + c * 16 + r15) * HDIM + 32 + g * 8);
            f32x4 z = {0.f, 0.f, 0.f, 0.f};
            z = __builtin_amdgcn_mfma_f32_16x16x32_bf16(qf[0], kf0, z, 0, 0, 0);
            s[c] = __builtin_amdgcn_mfma_f32_16x16x32_bf16(qf[1], kf1, z, 0, 0, 0);
        }
        const bool masked = (kv0 + 31 > q0);
        #pragma unroll
        for (int c = 0; c < 2; ++c)
            #pragma unroll
            for (int i = 0; i < 4; ++i) {
                float v = s[c][i] * 0.125f;
                if (masked && (kv0 + c * 16 + r15 > q0 + g * 4 + i)) v = -INFINITY;
                s[c][i] = v;
            }

        // row-wise max over kv (16 lanes within group share a row set)
        float vmax[4];
        #pragma unroll
        for (int i = 0; i < 4; ++i) vmax[i] = fmaxf(s[0][i], s[1][i]);
        #pragma unroll
        for (int off = 1; off < 16; off <<= 1)
            #pragma unroll
            for (int i = 0; i < 4; ++i) vmax[i] = fmaxf(vmax[i], __shfl_xor(vmax[i], off));

        float p0[4], p1[4], lsum[4], scl[4];
        #pragma unroll
        for (int i = 0; i < 4; ++i) {
            const float mn = fmaxf(mrow[i], vmax[i]);
            scl[i] = __expf(mrow[i] - mn);
            mrow[i] = mn;
            p0[i] = __expf(s[0][i] - mn);
            p1[i] = __expf(s[1][i] - mn);
            lsum[i] = p0[i] + p1[i];
        }
        #pragma unroll
        for (int off = 1; off < 16; off <<= 1)
            #pragma unroll
            for (int i = 0; i < 4; ++i) lsum[i] += __shfl_xor(lsum[i], off);
        #pragma unroll
        for (int i = 0; i < 4; ++i) lrow[i] = lrow[i] * scl[i] + lsum[i];

        // P -> LDS in A-frag (k-grouped) layout: element (row,col) at [col/8][row][col%8]
        __syncthreads();
        #pragma unroll
        for (int i = 0; i < 4; ++i) {
            const int row = g * 4 + i;
            Ps[r15 >> 3][row][r15 & 7] = f2bf(p0[i]);
            Ps[2 + (r15 >> 3)][row][r15 & 7] = f2bf(p1[i]);
        }
        __syncthreads();
        const bfr8 pf = *(const bfr8*)&Ps[g][r15][0];

        // rescale O, then O += P @ V  (B-frag from VT rows: contiguous)
        #pragma unroll
        for (int ch = 0; ch < 4; ++ch)
            #pragma unroll
            for (int i = 0; i < 4; ++i) o[ch][i] *= scl[i];
        #pragma unroll
        for (int ch = 0; ch < 4; ++ch) {
            bfr8 vf = *(const bfr8*)(Vb + (size_t)(ch * 16 + r15) * SEQ + kv0 + g * 8);
            o[ch] = __builtin_amdgcn_mfma_f32_16x16x32_bf16(pf, vf, o[ch], 0, 0, 0);
        }
    }

    const int b = bh >> 4, h = bh & 15;
    float inv[4];
    #pragma unroll
    for (int i = 0; i < 4; ++i) inv[i] = 1.f / lrow[i];
    #pragma unroll
    for (int ch = 0; ch < 4; ++ch)
        #pragma unroll
        for (int i = 0; i < 4; ++i) {
            const int row = q0 + g * 4 + i;
            const int col = h * HDIM + ch * 16 + r15;
            O[((size_t)b * SEQ + row) * DMODEL + col] = f2bf(o[ch][i] * inv[i]);
        }
}

// ---------------- launch ----------------
extern "C" void kernel_launch(void* const* d_in, const int* in_sizes, int n_in,
                              void* d_out, int out_size, void* d_ws, size_t ws_size,
                              hipStream_t stream) {
    const float* x   = (const float*)d_in[0];
    const float* w_q = (const float*)d_in[1];
    const float* b_q = (const float*)d_in[2];
    const float* w_k = (const float*)d_in[3];
    const float* b_k = (const float*)d_in[4];
    const float* w_v = (const float*)d_in[5];
    const float* b_v = (const float*)d_in[6];
    const float* w_o = (const float*)d_in[7];
    const float* b_o = (const float*)d_in[8];
    float* out = (float*)d_out;

    const size_t NX = (size_t)MROWS * DMODEL;   // 4,194,304
    const size_t NW = (size_t)DMODEL * DMODEL;  // 1,048,576
    unsigned short* xb  = (unsigned short*)d_ws;
    unsigned short* wqb = xb + NX;
    unsigned short* wkb = wqb + NW;
    unsigned short* wvb = wkb + NW;
    unsigned short* wob = wvb + NW;
    unsigned short* Qw  = wob + NW;   // [B,H,T,64]
    unsigned short* Kw  = Qw + NX;    // [B,H,T,64]
    unsigned short* VTw = Kw + NX;    // [B,H,64,T]
    unsigned short* Ow  = VTw + NX;   // [B,T,1024]

    cast_bf16<<<1024, 256, 0, stream>>>(x,   xb,  (int)NX);
    cast_bf16<<<512,  256, 0, stream>>>(w_q, wqb, (int)NW);
    cast_bf16<<<512,  256, 0, stream>>>(w_k, wkb, (int)NW);
    cast_bf16<<<512,  256, 0, stream>>>(w_v, wvb, (int)NW);
    cast_bf16<<<512,  256, 0, stream>>>(w_o, wob, (int)NW);

    dim3 gGrid(DMODEL / 128, MROWS / 128);   // (8, 32)
    gemm_bf16<<<gGrid, 256, 0, stream>>>(xb, wqb, b_q, Qw, 0);
    gemm_bf16<<<gGrid, 256, 0, stream>>>(xb, wkb, b_k, Kw, 0);
    gemm_bf16<<<gGrid, 256, 0, stream>>>(xb, wvb, b_v, VTw, 1);

    dim3 aGrid(SEQ / 16, BATCH * NHEADS);    // (128, 32)
    attn_mfma<<<aGrid, 64, 0, stream>>>(Qw, Kw, VTw, Ow);

    gemm_bf16<<<gGrid, 256, 0, stream>>>(Ow, wob, b_o, out, 2);
}

// Round 4
// 217.436 us; speedup vs baseline: 10.1666x; 1.8809x over previous
//
#include <hip/hip_runtime.h>
#include <hip/hip_bf16.h>
#include <math.h>

#define BATCH 2
#define SEQ   2048
#define DMODEL 1024
#define NHEADS 16
#define HDIM  64
#define MROWS (BATCH*SEQ)   // 4096

typedef __attribute__((ext_vector_type(8))) short bfr8;   // 8 bf16 (4 VGPRs)
typedef __attribute__((ext_vector_type(4))) float f32x4;  // MFMA C/D

__device__ inline unsigned short f2bf(float f) {
    union { float f; unsigned u; } v; v.f = f;
    unsigned r = v.u + 0x7FFFu + ((v.u >> 16) & 1u);   // RNE
    return (unsigned short)(r >> 16);
}

__device__ inline void gload16(const unsigned short* g, unsigned short* l) {
    __builtin_amdgcn_global_load_lds((const __attribute__((address_space(1))) void*)g,
        (__attribute__((address_space(3))) void*)l, 16, 0, 0);
}

// ---------------- cast fp32 -> bf16 ----------------
__global__ __launch_bounds__(256) void cast_bf16(const float* __restrict__ in,
                                                 unsigned short* __restrict__ out, int n) {
    int i = (blockIdx.x * 256 + threadIdx.x) * 4;
    const int stride = gridDim.x * 256 * 4;
    for (; i < n; i += stride) {
        float4 v = *(const float4*)(in + i);
        ushort4 o;
        o.x = f2bf(v.x); o.y = f2bf(v.y); o.z = f2bf(v.z); o.w = f2bf(v.w);
        *(ushort4*)(out + i) = o;
    }
}

// ---------------- bf16 MFMA GEMM: Y = A @ W^T + bias ----------------
// Tile BM x 128, BK=32, 4 waves.
// MODE 0: N=3072 fused QKV; col/1024 selects proj; Q,K -> [B,H,T,64], V -> [B,H,64,T]
// MODE 2: N=1024, fp32 linear output [4096,1024]
template<int BM, int MODE>
__global__ __launch_bounds__(256) void gemm_bf16(
    const unsigned short* __restrict__ A, const unsigned short* __restrict__ W,
    const float* __restrict__ bias, void* __restrict__ Y)
{
    __shared__ __align__(16) unsigned short As[2][4][BM][8];
    __shared__ __align__(16) unsigned short Bs[2][4][128][8];

    const int tid = threadIdx.x;
    const int l = tid & 63, w = tid >> 6;
    const int wr = w >> 1, wc = w & 1;
    const int m0 = blockIdx.y * BM, n0 = blockIdx.x * 128;
    const int r15 = l & 15, g = l >> 4;
    constexpr int MR = BM / 32;            // a-frags per wave

    f32x4 acc[MR][4] = {};

    auto stage = [&](int buf, int k0) {
        #pragma unroll
        for (int s = 0; s < BM / 64; ++s) {
            int idx = s * 256 + tid;             // A granules: 4*BM
            int row = idx % BM, kg = idx / BM;
            gload16(A + (size_t)(m0 + row) * 1024 + k0 + kg * 8, &As[buf][kg][row][0]);
        }
        #pragma unroll
        for (int s = 0; s < 2; ++s) {
            int idx = s * 256 + tid;             // B granules: 512
            int row = idx & 127, kg = idx >> 7;
            gload16(W + (size_t)(n0 + row) * 1024 + k0 + kg * 8, &Bs[buf][kg][row][0]);
        }
    };

    stage(0, 0);
    __syncthreads();

    for (int t = 0; t < 32; ++t) {
        const int buf = t & 1;
        if (t + 1 < 32) stage(buf ^ 1, (t + 1) * 32);
        bfr8 a[MR], b[4];
        #pragma unroll
        for (int m = 0; m < MR; ++m)
            a[m] = *(const bfr8*)&As[buf][g][wr * (BM / 2) + m * 16 + r15][0];
        #pragma unroll
        for (int n = 0; n < 4; ++n)
            b[n] = *(const bfr8*)&Bs[buf][g][wc * 64 + n * 16 + r15][0];
        #pragma unroll
        for (int m = 0; m < MR; ++m)
            #pragma unroll
            for (int n = 0; n < 4; ++n)
                acc[m][n] = __builtin_amdgcn_mfma_f32_16x16x32_bf16(a[m], b[n], acc[m][n], 0, 0, 0);
        __syncthreads();
    }

    const size_t NX = (size_t)MROWS * DMODEL;
    #pragma unroll
    for (int m = 0; m < MR; ++m) {
        const int rowb = m0 + wr * (BM / 2) + m * 16 + g * 4;
        #pragma unroll
        for (int n = 0; n < 4; ++n) {
            const int col = n0 + wc * 64 + n * 16 + r15;
            const float bc = bias[col];
            #pragma unroll
            for (int i = 0; i < 4; ++i) {
                const float v = acc[m][n][i] + bc;
                const int rr = rowb + i;
                if (MODE == 2) {
                    ((float*)Y)[(size_t)rr * 1024 + col] = v;
                } else {
                    const int bb = rr >> 11, tt = rr & 2047;
                    const int proj = col >> 10, within = col & 1023;
                    const int hh = within >> 6, dd = within & 63;
                    unsigned short* dst = (unsigned short*)Y + (size_t)proj * NX;
                    size_t idx;
                    if (proj < 2)
                        idx = (((size_t)bb * NHEADS + hh) * SEQ + tt) * HDIM + dd;
                    else
                        idx = (((size_t)bb * NHEADS + hh) * HDIM + dd) * SEQ + tt;
                    dst[idx] = f2bf(v);
                }
            }
        }
    }
}

// ---------------- MFMA flash attention (causal) ----------------
// Q,K: [B,H,T,64] bf16; VT: [B,H,64,T] bf16; O: [B,T,1024] bf16.
// Block: 4 waves, 64 q-rows (wave w owns rows q0+16w..+15). KV tile 64,
// double-buffered in LDS (XOR-swizzled via pre-swizzled global source).
// Longest blocks (high q0) dispatched first for load balance.
__global__ __launch_bounds__(256, 4) void attn_mfma(
    const unsigned short* __restrict__ Q, const unsigned short* __restrict__ K,
    const unsigned short* __restrict__ VT, unsigned short* __restrict__ O)
{
    __shared__ __align__(16) unsigned short Ks[2][64][64];   // [kv][d] (granule-swizzled)
    __shared__ __align__(16) unsigned short Vs[2][64][64];   // [d][kv] (granule-swizzled)
    __shared__ __align__(16) unsigned short Ps[4][8][16][8]; // per-wave P in A-frag layout

    const int tid = threadIdx.x;
    const int l = tid & 63, w = tid >> 6;
    const int r15 = l & 15, g2 = l >> 4;
    const int q0 = SEQ - 64 - blockIdx.x * 64;   // descending work
    const int bh = blockIdx.y;

    const unsigned short* Qb = Q + (size_t)bh * SEQ * HDIM;
    const unsigned short* Kb = K + (size_t)bh * SEQ * HDIM;
    const unsigned short* Vb = VT + (size_t)bh * HDIM * SEQ;

    bfr8 qf[2];
    qf[0] = *(const bfr8*)(Qb + (size_t)(q0 + w * 16 + r15) * HDIM + g2 * 8);
    qf[1] = *(const bfr8*)(Qb + (size_t)(q0 + w * 16 + r15) * HDIM + 32 + g2 * 8);

    auto stage = [&](int buf, int kv0) {
        #pragma unroll
        for (int s = 0; s < 2; ++s) {
            int idx = s * 256 + tid;               // 512 granules each
            int row = idx >> 3, gs = idx & 7;
            gload16(Kb + (size_t)(kv0 + row) * HDIM + ((gs ^ (row & 7)) * 8),
                    &Ks[buf][row][gs * 8]);
            gload16(Vb + (size_t)row * SEQ + kv0 + ((gs ^ (row & 7)) * 8),
                    &Vs[buf][row][gs * 8]);
        }
    };

    f32x4 o[4] = {};
    float mrow[4], lrow[4];
    #pragma unroll
    for (int i = 0; i < 4; ++i) { mrow[i] = -INFINITY; lrow[i] = 0.f; }

    const int ntiles = q0 / 64 + 1;
    stage(0, 0);
    __syncthreads();

    for (int kt = 0; kt < ntiles; ++kt) {
        const int kv0 = kt * 64, buf = kt & 1;
        if (kt + 1 < ntiles) stage(buf ^ 1, kv0 + 64);

        // ---- S = Q @ K^T ----
        f32x4 s[4];
        #pragma unroll
        for (int c = 0; c < 4; ++c) {
            const int kv = c * 16 + r15;
            const bfr8 kf0 = *(const bfr8*)&Ks[buf][kv][(g2 ^ (kv & 7)) * 8];
            const bfr8 kf1 = *(const bfr8*)&Ks[buf][kv][((4 + g2) ^ (kv & 7)) * 8];
            f32x4 z = {0.f, 0.f, 0.f, 0.f};
            z = __builtin_amdgcn_mfma_f32_16x16x32_bf16(qf[0], kf0, z, 0, 0, 0);
            s[c] = __builtin_amdgcn_mfma_f32_16x16x32_bf16(qf[1], kf1, z, 0, 0, 0);
        }
        const bool last = (kt == ntiles - 1);
        #pragma unroll
        for (int c = 0; c < 4; ++c)
            #pragma unroll
            for (int i = 0; i < 4; ++i) {
                float v = s[c][i] * 0.125f;
                if (last && (kv0 + c * 16 + r15 > q0 + w * 16 + g2 * 4 + i)) v = -INFINITY;
                s[c][i] = v;
            }

        // ---- online softmax (rows live in 16-lane groups) ----
        float vmax[4], scl[4], ls[4];
        #pragma unroll
        for (int i = 0; i < 4; ++i)
            vmax[i] = fmaxf(fmaxf(s[0][i], s[1][i]), fmaxf(s[2][i], s[3][i]));
        #pragma unroll
        for (int off = 1; off < 16; off <<= 1)
            #pragma unroll
            for (int i = 0; i < 4; ++i)
                vmax[i] = fmaxf(vmax[i], __shfl_xor(vmax[i], off));
        #pragma unroll
        for (int i = 0; i < 4; ++i) {
            const float mn = fmaxf(mrow[i], vmax[i]);
            scl[i] = __expf(mrow[i] - mn);
            mrow[i] = mn;
            ls[i] = 0.f;
        }
        #pragma unroll
        for (int c = 0; c < 4; ++c) {
            const int kg = c * 2 + (r15 >> 3);
            #pragma unroll
            for (int i = 0; i < 4; ++i) {
                const float p = __expf(s[c][i] - mrow[i]);
                ls[i] += p;
                Ps[w][kg][g2 * 4 + i][r15 & 7] = f2bf(p);   // wave-private, no barrier
            }
        }
        #pragma unroll
        for (int off = 1; off < 16; off <<= 1)
            #pragma unroll
            for (int i = 0; i < 4; ++i)
                ls[i] += __shfl_xor(ls[i], off);
        #pragma unroll
        for (int i = 0; i < 4; ++i)
            lrow[i] = lrow[i] * scl[i] + ls[i];

        // ---- O = O*scl + P @ V ----
        #pragma unroll
        for (int ch = 0; ch < 4; ++ch)
            #pragma unroll
            for (int i = 0; i < 4; ++i)
                o[ch][i] *= scl[i];
        const bfr8 pf0 = *(const bfr8*)&Ps[w][g2][r15][0];
        const bfr8 pf1 = *(const bfr8*)&Ps[w][4 + g2][r15][0];
        #pragma unroll
        for (int ch = 0; ch < 4; ++ch) {
            const int d = ch * 16 + r15;
            const bfr8 vf0 = *(const bfr8*)&Vs[buf][d][(g2 ^ (d & 7)) * 8];
            const bfr8 vf1 = *(const bfr8*)&Vs[buf][d][((4 + g2) ^ (d & 7)) * 8];
            o[ch] = __builtin_amdgcn_mfma_f32_16x16x32_bf16(pf0, vf0, o[ch], 0, 0, 0);
            o[ch] = __builtin_amdgcn_mfma_f32_16x16x32_bf16(pf1, vf1, o[ch], 0, 0, 0);
        }
        __syncthreads();   // protects K/V buffers (and drains staged loads)
    }

    const int b = bh >> 4, h = bh & 15;
    #pragma unroll
    for (int i = 0; i < 4; ++i) {
        const float inv = 1.f / lrow[i];
        const int row = q0 + w * 16 + g2 * 4 + i;
        #pragma unroll
        for (int ch = 0; ch < 4; ++ch) {
            const int col = h * HDIM + ch * 16 + r15;
            O[((size_t)b * SEQ + row) * DMODEL + col] = f2bf(o[ch][i] * inv);
        }
    }
}

// ---------------- launch ----------------
extern "C" void kernel_launch(void* const* d_in, const int* in_sizes, int n_in,
                              void* d_out, int out_size, void* d_ws, size_t ws_size,
                              hipStream_t stream) {
    const float* x   = (const float*)d_in[0];
    const float* w_q = (const float*)d_in[1];
    const float* b_q = (const float*)d_in[2];
    const float* w_k = (const float*)d_in[3];
    const float* b_k = (const float*)d_in[4];
    const float* w_v = (const float*)d_in[5];
    const float* b_v = (const float*)d_in[6];
    const float* w_o = (const float*)d_in[7];
    const float* b_o = (const float*)d_in[8];
    float* out = (float*)d_out;

    const size_t NX = (size_t)MROWS * DMODEL;   // 4,194,304
    const size_t NW = (size_t)DMODEL * DMODEL;  // 1,048,576
    unsigned short* xb    = (unsigned short*)d_ws;
    unsigned short* wcomb = xb + NX;            // [3072][1024] = wq|wk|wv
    unsigned short* wob   = wcomb + 3 * NW;
    unsigned short* Qw    = wob + NW;           // [B,H,T,64]
    unsigned short* Kw    = Qw + NX;            // [B,H,T,64]
    unsigned short* VTw   = Kw + NX;            // [B,H,64,T]
    unsigned short* Ow    = VTw + NX;           // [B,T,1024]
    float* bias3          = (float*)(Ow + NX);  // [3072] fp32

    cast_bf16<<<1024, 256, 0, stream>>>(x,   xb, (int)NX);
    cast_bf16<<<512,  256, 0, stream>>>(w_q, wcomb,          (int)NW);
    cast_bf16<<<512,  256, 0, stream>>>(w_k, wcomb + NW,     (int)NW);
    cast_bf16<<<512,  256, 0, stream>>>(w_v, wcomb + 2 * NW, (int)NW);
    cast_bf16<<<512,  256, 0, stream>>>(w_o, wob, (int)NW);
    hipMemcpyAsync(bias3,        b_q, 1024 * sizeof(float), hipMemcpyDeviceToDevice, stream);
    hipMemcpyAsync(bias3 + 1024, b_k, 1024 * sizeof(float), hipMemcpyDeviceToDevice, stream);
    hipMemcpyAsync(bias3 + 2048, b_v, 1024 * sizeof(float), hipMemcpyDeviceToDevice, stream);

    // fused QKV projection: [4096,1024] @ [3072,1024]^T
    gemm_bf16<128, 0><<<dim3(24, 32), 256, 0, stream>>>(xb, wcomb, bias3, Qw);

    attn_mfma<<<dim3(32, 32), 256, 0, stream>>>(Qw, Kw, VTw, Ow);

    // output projection: [4096,1024] @ [1024,1024]^T -> fp32
    gemm_bf16<64, 2><<<dim3(8, 64), 256, 0, stream>>>(Ow, wob, b_o, out);
}

// Round 5
// 190.870 us; speedup vs baseline: 11.5816x; 1.1392x over previous
//
#include <hip/hip_runtime.h>
#include <hip/hip_bf16.h>
#include <math.h>

#define BATCH 2
#define SEQ   2048
#define DMODEL 1024
#define NHEADS 16
#define HDIM  64
#define MROWS (BATCH*SEQ)   // 4096
#define QSCALE 0.1803368801111204f   // 0.125 * log2(e); attention uses exp2

typedef __attribute__((ext_vector_type(8))) short bfr8;   // 8 bf16 (4 VGPRs)
typedef __attribute__((ext_vector_type(4))) float f32x4;  // MFMA C/D

__device__ inline unsigned short f2bf(float f) {
    union { float f; unsigned u; } v; v.f = f;
    unsigned r = v.u + 0x7FFFu + ((v.u >> 16) & 1u);   // RNE
    return (unsigned short)(r >> 16);
}

__device__ inline unsigned pack2bf(float a, float b) {   // low=a, high=b
    union { __hip_bfloat162 h; unsigned u; } cv;
    cv.h = __float22bfloat162_rn(float2{a, b});
    return cv.u;
}

__device__ inline void gload16(const unsigned short* g, unsigned short* l) {
    __builtin_amdgcn_global_load_lds((const __attribute__((address_space(1))) void*)g,
        (__attribute__((address_space(3))) void*)l, 16, 0, 0);
}

// ---------------- casts fp32 -> bf16 ----------------
__global__ __launch_bounds__(256) void cast_bf16(const float* __restrict__ in,
                                                 unsigned short* __restrict__ out, int n) {
    int i = (blockIdx.x * 256 + threadIdx.x) * 4;
    const int stride = gridDim.x * 256 * 4;
    for (; i < n; i += stride) {
        float4 v = *(const float4*)(in + i);
        ushort4 o;
        o.x = f2bf(v.x); o.y = f2bf(v.y); o.z = f2bf(v.z); o.w = f2bf(v.w);
        *(ushort4*)(out + i) = o;
    }
}

// 4 weight matrices (each 2^20 elems) -> contiguous dst
__global__ __launch_bounds__(256) void cast4_bf16(
    const float* __restrict__ a, const float* __restrict__ b,
    const float* __restrict__ c, const float* __restrict__ d,
    unsigned short* __restrict__ out) {
    const int NW = 1 << 20;
    int i = (blockIdx.x * 256 + threadIdx.x) * 4;
    const int stride = gridDim.x * 256 * 4;
    for (; i < 4 * NW; i += stride) {
        const int seg = i >> 20;
        const float* src = seg == 0 ? a : seg == 1 ? b : seg == 2 ? c : d;
        float4 v = *(const float4*)(src + (i & (NW - 1)));
        ushort4 o;
        o.x = f2bf(v.x); o.y = f2bf(v.y); o.z = f2bf(v.z); o.w = f2bf(v.w);
        *(ushort4*)(out + i) = o;
    }
}

// ---------------- bf16 MFMA GEMM: Y = A @ W^T + bias ----------------
// Tile BM x 128, BK=32, 4 waves.
// MODE 0: N=3072 fused QKV; proj=col/1024; Q scaled by QSCALE; Q,K->[B,H,T,64], V->[B,H,64,T]
// MODE 2: N=1024, fp32 linear output [4096,1024], bias b0
template<int BM, int MODE>
__global__ __launch_bounds__(256) void gemm_bf16(
    const unsigned short* __restrict__ A, const unsigned short* __restrict__ W,
    const float* __restrict__ b0, const float* __restrict__ b1,
    const float* __restrict__ b2, void* __restrict__ Y)
{
    __shared__ __align__(16) unsigned short As[2][4][BM][8];
    __shared__ __align__(16) unsigned short Bs[2][4][128][8];

    const int tid = threadIdx.x;
    const int l = tid & 63, w = tid >> 6;
    const int wr = w >> 1, wc = w & 1;
    const int m0 = blockIdx.y * BM, n0 = blockIdx.x * 128;
    const int r15 = l & 15, g = l >> 4;
    constexpr int MR = BM / 32;

    f32x4 acc[MR][4] = {};

    auto stage = [&](int buf, int k0) {
        #pragma unroll
        for (int s = 0; s < BM / 64; ++s) {
            int idx = s * 256 + tid;
            int row = idx % BM, kg = idx / BM;
            gload16(A + (size_t)(m0 + row) * 1024 + k0 + kg * 8, &As[buf][kg][row][0]);
        }
        #pragma unroll
        for (int s = 0; s < 2; ++s) {
            int idx = s * 256 + tid;
            int row = idx & 127, kg = idx >> 7;
            gload16(W + (size_t)(n0 + row) * 1024 + k0 + kg * 8, &Bs[buf][kg][row][0]);
        }
    };

    stage(0, 0);
    __syncthreads();

    for (int t = 0; t < 32; ++t) {
        const int buf = t & 1;
        if (t + 1 < 32) stage(buf ^ 1, (t + 1) * 32);
        bfr8 a[MR], b[4];
        #pragma unroll
        for (int m = 0; m < MR; ++m)
            a[m] = *(const bfr8*)&As[buf][g][wr * (BM / 2) + m * 16 + r15][0];
        #pragma unroll
        for (int n = 0; n < 4; ++n)
            b[n] = *(const bfr8*)&Bs[buf][g][wc * 64 + n * 16 + r15][0];
        #pragma unroll
        for (int m = 0; m < MR; ++m)
            #pragma unroll
            for (int n = 0; n < 4; ++n)
                acc[m][n] = __builtin_amdgcn_mfma_f32_16x16x32_bf16(a[m], b[n], acc[m][n], 0, 0, 0);
        __syncthreads();
    }

    const size_t NX = (size_t)MROWS * DMODEL;
    #pragma unroll
    for (int m = 0; m < MR; ++m) {
        const int rowb = m0 + wr * (BM / 2) + m * 16 + g * 4;
        #pragma unroll
        for (int n = 0; n < 4; ++n) {
            const int col = n0 + wc * 64 + n * 16 + r15;
            const int proj = col >> 10, within = col & 1023;
            const float bc = (MODE == 2) ? b0[col]
                           : (proj == 0 ? b0[within] : proj == 1 ? b1[within] : b2[within]);
            #pragma unroll
            for (int i = 0; i < 4; ++i) {
                float v = acc[m][n][i] + bc;
                const int rr = rowb + i;
                if (MODE == 2) {
                    ((float*)Y)[(size_t)rr * 1024 + col] = v;
                } else {
                    if (proj == 0) v *= QSCALE;
                    const int bb = rr >> 11, tt = rr & 2047;
                    const int hh = within >> 6, dd = within & 63;
                    unsigned short* dst = (unsigned short*)Y + (size_t)proj * NX;
                    size_t idx;
                    if (proj < 2)
                        idx = (((size_t)bb * NHEADS + hh) * SEQ + tt) * HDIM + dd;
                    else
                        idx = (((size_t)bb * NHEADS + hh) * HDIM + dd) * SEQ + tt;
                    dst[idx] = f2bf(v);
                }
            }
        }
    }
}

// ---------------- MFMA flash attention (causal, swapped-QK) ----------------
// Q,K: [B,H,T,64] bf16 (Q pre-scaled by 0.125*log2e); VT: [B,H,64,T]; O: [B,T,1024] bf16.
// Block: 4 waves x 32 q-rows = 128 rows. KV tile 64, double-buffered LDS
// (XOR-swizzled via pre-swizzled global source). S^T = mfma(K,Q): kv on C rows
// (lane-local, packable), q on C cols (lane r15).
__global__ __launch_bounds__(256, 2) void attn_mfma(
    const unsigned short* __restrict__ Q, const unsigned short* __restrict__ K,
    const unsigned short* __restrict__ VT, unsigned short* __restrict__ O)
{
    __shared__ __align__(16) unsigned short Ks[2][64][64];      // [kv][d] granule-swizzled
    __shared__ __align__(16) unsigned short Vs[2][64][64];      // [d][kv] granule-swizzled
    __shared__ __align__(16) unsigned short Ps[4][2][16][8][8]; // [wave][rf][q][kg^...][e]

    const int tid = threadIdx.x;
    const int l = tid & 63, w = tid >> 6;
    const int r15 = l & 15, g2 = (l >> 4) & 3;
    const int q0 = SEQ - 128 - blockIdx.x * 128;   // descending work
    const int qw = q0 + w * 32;
    const int bh = blockIdx.y;

    const unsigned short* Qb = Q + (size_t)bh * SEQ * HDIM;
    const unsigned short* Kb = K + (size_t)bh * SEQ * HDIM;
    const unsigned short* Vb = VT + (size_t)bh * HDIM * SEQ;

    bfr8 qf[2][2];   // [rf][kslice]  (B-frag: lane holds Q[qw+rf*16+r15][ks*32+g2*8..+7])
    #pragma unroll
    for (int rf = 0; rf < 2; ++rf)
        #pragma unroll
        for (int ks = 0; ks < 2; ++ks)
            qf[rf][ks] = *(const bfr8*)(Qb + (size_t)(qw + rf * 16 + r15) * HDIM + ks * 32 + g2 * 8);

    auto stage = [&](int buf, int kv0) {
        #pragma unroll
        for (int s = 0; s < 2; ++s) {
            int idx = s * 256 + tid;
            int row = idx >> 3, gs = idx & 7;
            gload16(Kb + (size_t)(kv0 + row) * HDIM + ((gs ^ (row & 7)) * 8), &Ks[buf][row][gs * 8]);
            gload16(Vb + (size_t)row * SEQ + kv0 + ((gs ^ (row & 7)) * 8), &Vs[buf][row][gs * 8]);
        }
    };

    f32x4 o[4][2] = {};            // [d-chunk][rf]
    float mrow[2] = {-INFINITY, -INFINITY}, lrow[2] = {0.f, 0.f};

    const int ntiles = q0 / 64 + 2;
    stage(0, 0);
    __syncthreads();

    for (int kt = 0; kt < ntiles; ++kt) {
        const int kv0 = kt * 64, buf = kt & 1;
        if (kt + 1 < ntiles) stage(buf ^ 1, kv0 + 64);

        // ---- S^T = K @ Q^T : s[c][rf], C row = kv-off (c*16+g2*4+i), col = q-off (r15)
        f32x4 s[4][2];
        #pragma unroll
        for (int c = 0; c < 4; ++c) {
            const int rk = c * 16 + r15;
            const bfr8 kf0 = *(const bfr8*)&Ks[buf][rk][(g2 ^ (r15 & 7)) * 8];
            const bfr8 kf1 = *(const bfr8*)&Ks[buf][rk][((4 + g2) ^ (r15 & 7)) * 8];
            #pragma unroll
            for (int rf = 0; rf < 2; ++rf) {
                f32x4 z = {0.f, 0.f, 0.f, 0.f};
                z = __builtin_amdgcn_mfma_f32_16x16x32_bf16(kf0, qf[rf][0], z, 0, 0, 0);
                s[c][rf] = __builtin_amdgcn_mfma_f32_16x16x32_bf16(kf1, qf[rf][1], z, 0, 0, 0);
            }
        }

        if (kt >= ntiles - 2) {    // causal mask (only the 2 diagonal-straddling tiles)
            #pragma unroll
            for (int c = 0; c < 4; ++c)
                #pragma unroll
                for (int rf = 0; rf < 2; ++rf) {
                    const int q = qw + rf * 16 + r15;
                    #pragma unroll
                    for (int i = 0; i < 4; ++i)
                        if (kv0 + c * 16 + g2 * 4 + i > q) s[c][rf][i] = -INFINITY;
                }
        }

        float scl[2];
        #pragma unroll
        for (int rf = 0; rf < 2; ++rf) {
            // max over kv: in-lane (16 vals) then lanes r15, r15+16, +32, +48
            float tm = s[0][rf][0];
            #pragma unroll
            for (int c = 0; c < 4; ++c)
                #pragma unroll
                for (int i = 0; i < 4; ++i) tm = fmaxf(tm, s[c][rf][i]);
            tm = fmaxf(tm, __shfl_xor(tm, 16));
            tm = fmaxf(tm, __shfl_xor(tm, 32));
            const float mn = fmaxf(mrow[rf], tm);
            scl[rf] = exp2f(mrow[rf] - mn);
            mrow[rf] = mn;
            float ls = 0.f;
            #pragma unroll
            for (int c = 0; c < 4; ++c)
                #pragma unroll
                for (int i = 0; i < 4; ++i) {
                    const float p = exp2f(s[c][rf][i] - mn);
                    s[c][rf][i] = p;
                    ls += p;
                }
            ls += __shfl_xor(ls, 16);
            ls += __shfl_xor(ls, 32);
            lrow[rf] = lrow[rf] * scl[rf] + ls;
            // pack pairs along kv -> b32 LDS stores (A-frag layout, kg-XOR swizzle)
            #pragma unroll
            for (int c = 0; c < 4; ++c) {
                const int kgw = (c * 2 + (g2 >> 1)) ^ (r15 & 7);
                #pragma unroll
                for (int p = 0; p < 2; ++p) {
                    unsigned pk = pack2bf(s[c][rf][2 * p], s[c][rf][2 * p + 1]);
                    *(unsigned*)&Ps[w][rf][r15][kgw][(g2 & 1) * 4 + 2 * p] = pk;
                }
            }
        }

        // ---- O = O*scl + P @ V ----
        #pragma unroll
        for (int rf = 0; rf < 2; ++rf) {
            float sb[4];
            #pragma unroll
            for (int i = 0; i < 4; ++i) sb[i] = __shfl(scl[rf], g2 * 4 + i, 16);
            #pragma unroll
            for (int ch = 0; ch < 4; ++ch)
                #pragma unroll
                for (int i = 0; i < 4; ++i) o[ch][rf][i] *= sb[i];
        }
        bfr8 pf[2][2];
        #pragma unroll
        for (int rf = 0; rf < 2; ++rf)
            #pragma unroll
            for (int ks = 0; ks < 2; ++ks)
                pf[rf][ks] = *(const bfr8*)&Ps[w][rf][r15][(ks * 4 + g2) ^ (r15 & 7)][0];
        #pragma unroll
        for (int ch = 0; ch < 4; ++ch) {
            const int d = ch * 16 + r15;
            const bfr8 vf0 = *(const bfr8*)&Vs[buf][d][(g2 ^ (r15 & 7)) * 8];
            const bfr8 vf1 = *(const bfr8*)&Vs[buf][d][((4 + g2) ^ (r15 & 7)) * 8];
            #pragma unroll
            for (int rf = 0; rf < 2; ++rf) {
                o[ch][rf] = __builtin_amdgcn_mfma_f32_16x16x32_bf16(pf[rf][0], vf0, o[ch][rf], 0, 0, 0);
                o[ch][rf] = __builtin_amdgcn_mfma_f32_16x16x32_bf16(pf[rf][1], vf1, o[ch][rf], 0, 0, 0);
            }
        }
        __syncthreads();   // protects K/V buffers (drains staged loads)
    }

    const int b = bh >> 4, h = bh & 15;
    #pragma unroll
    for (int rf = 0; rf < 2; ++rf) {
        const float inv = 1.f / lrow[rf];
        float ib[4];
        #pragma unroll
        for (int i = 0; i < 4; ++i) ib[i] = __shfl(inv, g2 * 4 + i, 16);
        #pragma unroll
        for (int i = 0; i < 4; ++i) {
            const int row = qw + rf * 16 + g2 * 4 + i;
            #pragma unroll
            for (int ch = 0; ch < 4; ++ch) {
                const int col = h * HDIM + ch * 16 + r15;
                O[((size_t)b * SEQ + row) * DMODEL + col] = f2bf(o[ch][rf][i] * ib[i]);
            }
        }
    }
}

// ---------------- launch ----------------
extern "C" void kernel_launch(void* const* d_in, const int* in_sizes, int n_in,
                              void* d_out, int out_size, void* d_ws, size_t ws_size,
                              hipStream_t stream) {
    const float* x   = (const float*)d_in[0];
    const float* w_q = (const float*)d_in[1];
    const float* b_q = (const float*)d_in[2];
    const float* w_k = (const float*)d_in[3];
    const float* b_k = (const float*)d_in[4];
    const float* w_v = (const float*)d_in[5];
    const float* b_v = (const float*)d_in[6];
    const float* w_o = (const float*)d_in[7];
    const float* b_o = (const float*)d_in[8];
    float* out = (float*)d_out;

    const size_t NX = (size_t)MROWS * DMODEL;   // 4,194,304
    const size_t NW = (size_t)DMODEL * DMODEL;  // 1,048,576 = 2^20
    unsigned short* xb    = (unsigned short*)d_ws;
    unsigned short* wcomb = xb + NX;            // [3072][1024] = wq|wk|wv, then wo
    unsigned short* wob   = wcomb + 3 * NW;
    unsigned short* Qw    = wob + NW;           // [B,H,T,64] (scaled)
    unsigned short* Kw    = Qw + NX;            // [B,H,T,64]
    unsigned short* VTw   = Kw + NX;            // [B,H,64,T]
    unsigned short* Ow    = VTw + NX;           // [B,T,1024]

    cast_bf16<<<1024, 256, 0, stream>>>(x, xb, (int)NX);
    cast4_bf16<<<2048, 256, 0, stream>>>(w_q, w_k, w_v, w_o, wcomb);

    // fused QKV projection: [4096,1024] @ [3072,1024]^T
    gemm_bf16<128, 0><<<dim3(24, 32), 256, 0, stream>>>(xb, wcomb, b_q, b_k, b_v, Qw);

    attn_mfma<<<dim3(16, 32), 256, 0, stream>>>(Qw, Kw, VTw, Ow);

    // output projection: [4096,1024] @ [1024,1024]^T -> fp32
    gemm_bf16<64, 2><<<dim3(8, 64), 256, 0, stream>>>(Ow, wob, b_o, nullptr, nullptr, out);
}

// Round 6
// 160.833 us; speedup vs baseline: 13.7445x; 1.1868x over previous
//
#include <hip/hip_runtime.h>
#include <hip/hip_bf16.h>
#include <math.h>

#define BATCH 2
#define SEQ   2048
#define DMODEL 1024
#define NHEADS 16
#define HDIM  64
#define MROWS (BATCH*SEQ)   // 4096
#define QSCALE 0.1803368801111204f   // 0.125 * log2(e); attention uses exp2

typedef __attribute__((ext_vector_type(8))) short bfr8;   // 8 bf16 (4 VGPRs)
typedef __attribute__((ext_vector_type(4))) float f32x4;  // MFMA C/D

__device__ inline unsigned short f2bf(float f) {
    union { float f; unsigned u; } v; v.f = f;
    unsigned r = v.u + 0x7FFFu + ((v.u >> 16) & 1u);   // RNE
    return (unsigned short)(r >> 16);
}

__device__ inline unsigned pack2bf(float a, float b) {   // low=a, high=b
    union { __hip_bfloat162 h; unsigned u; } cv;
    cv.h = __float22bfloat162_rn(float2{a, b});
    return cv.u;
}

__device__ inline void gload16(const unsigned short* g, unsigned short* l) {
    __builtin_amdgcn_global_load_lds((const __attribute__((address_space(1))) void*)g,
        (__attribute__((address_space(3))) void*)l, 16, 0, 0);
}

// ---------------- casts fp32 -> bf16 ----------------
__global__ __launch_bounds__(256) void cast_bf16(const float* __restrict__ in,
                                                 unsigned short* __restrict__ out, int n) {
    int i = (blockIdx.x * 256 + threadIdx.x) * 4;
    const int stride = gridDim.x * 256 * 4;
    for (; i < n; i += stride) {
        float4 v = *(const float4*)(in + i);
        ushort4 o;
        o.x = f2bf(v.x); o.y = f2bf(v.y); o.z = f2bf(v.z); o.w = f2bf(v.w);
        *(ushort4*)(out + i) = o;
    }
}

// 4 weight matrices (each 2^20 elems) -> contiguous dst
__global__ __launch_bounds__(256) void cast4_bf16(
    const float* __restrict__ a, const float* __restrict__ b,
    const float* __restrict__ c, const float* __restrict__ d,
    unsigned short* __restrict__ out) {
    const int NW = 1 << 20;
    int i = (blockIdx.x * 256 + threadIdx.x) * 4;
    const int stride = gridDim.x * 256 * 4;
    for (; i < 4 * NW; i += stride) {
        const int seg = i >> 20;
        const float* src = seg == 0 ? a : seg == 1 ? b : seg == 2 ? c : d;
        float4 v = *(const float4*)(src + (i & (NW - 1)));
        ushort4 o;
        o.x = f2bf(v.x); o.y = f2bf(v.y); o.z = f2bf(v.z); o.w = f2bf(v.w);
        *(ushort4*)(out + i) = o;
    }
}

// ---------------- bf16 MFMA GEMM: Y = A @ W^T + bias ----------------
// Tile BM x 128, BK=32, 4 waves.
// MODE 0: N=3072 fused QKV; proj=col/1024; Q scaled by QSCALE; Q,K->[B,H,T,64], V->[B,H,64,T]
// MODE 2: N=1024, fp32 linear output [4096,1024], bias b0
template<int BM, int MODE>
__global__ __launch_bounds__(256) void gemm_bf16(
    const unsigned short* __restrict__ A, const unsigned short* __restrict__ W,
    const float* __restrict__ b0, const float* __restrict__ b1,
    const float* __restrict__ b2, void* __restrict__ Y)
{
    __shared__ __align__(16) unsigned short As[2][4][BM][8];
    __shared__ __align__(16) unsigned short Bs[2][4][128][8];

    const int tid = threadIdx.x;
    const int l = tid & 63, w = tid >> 6;
    const int wr = w >> 1, wc = w & 1;
    const int m0 = blockIdx.y * BM, n0 = blockIdx.x * 128;
    const int r15 = l & 15, g = l >> 4;
    constexpr int MR = BM / 32;

    f32x4 acc[MR][4] = {};

    auto stage = [&](int buf, int k0) {
        #pragma unroll
        for (int s = 0; s < BM / 64; ++s) {
            int idx = s * 256 + tid;
            int row = idx % BM, kg = idx / BM;
            gload16(A + (size_t)(m0 + row) * 1024 + k0 + kg * 8, &As[buf][kg][row][0]);
        }
        #pragma unroll
        for (int s = 0; s < 2; ++s) {
            int idx = s * 256 + tid;
            int row = idx & 127, kg = idx >> 7;
            gload16(W + (size_t)(n0 + row) * 1024 + k0 + kg * 8, &Bs[buf][kg][row][0]);
        }
    };

    stage(0, 0);
    __syncthreads();

    for (int t = 0; t < 32; ++t) {
        const int buf = t & 1;
        if (t + 1 < 32) stage(buf ^ 1, (t + 1) * 32);
        bfr8 a[MR], b[4];
        #pragma unroll
        for (int m = 0; m < MR; ++m)
            a[m] = *(const bfr8*)&As[buf][g][wr * (BM / 2) + m * 16 + r15][0];
        #pragma unroll
        for (int n = 0; n < 4; ++n)
            b[n] = *(const bfr8*)&Bs[buf][g][wc * 64 + n * 16 + r15][0];
        #pragma unroll
        for (int m = 0; m < MR; ++m)
            #pragma unroll
            for (int n = 0; n < 4; ++n)
                acc[m][n] = __builtin_amdgcn_mfma_f32_16x16x32_bf16(a[m], b[n], acc[m][n], 0, 0, 0);
        __syncthreads();
    }

    const size_t NX = (size_t)MROWS * DMODEL;
    #pragma unroll
    for (int m = 0; m < MR; ++m) {
        const int rowb = m0 + wr * (BM / 2) + m * 16 + g * 4;
        #pragma unroll
        for (int n = 0; n < 4; ++n) {
            const int col = n0 + wc * 64 + n * 16 + r15;
            const int proj = col >> 10, within = col & 1023;
            const float bc = (MODE == 2) ? b0[col]
                           : (proj == 0 ? b0[within] : proj == 1 ? b1[within] : b2[within]);
            #pragma unroll
            for (int i = 0; i < 4; ++i) {
                float v = acc[m][n][i] + bc;
                const int rr = rowb + i;
                if (MODE == 2) {
                    ((float*)Y)[(size_t)rr * 1024 + col] = v;
                } else {
                    if (proj == 0) v *= QSCALE;
                    const int bb = rr >> 11, tt = rr & 2047;
                    const int hh = within >> 6, dd = within & 63;
                    unsigned short* dst = (unsigned short*)Y + (size_t)proj * NX;
                    size_t idx;
                    if (proj < 2)
                        idx = (((size_t)bb * NHEADS + hh) * SEQ + tt) * HDIM + dd;
                    else
                        idx = (((size_t)bb * NHEADS + hh) * HDIM + dd) * SEQ + tt;
                    dst[idx] = f2bf(v);
                }
            }
        }
    }
}

// ---------------- MFMA flash attention (causal, fully lane-local softmax) ----------------
// Q,K: [B,H,T,64] bf16 (Q pre-scaled by 0.125*log2e); VT: [B,H,64,T]; O: [B,T,1024] bf16.
// Block: 4 waves x 16 q-rows = 64 q. S^T = mfma(K, Q^T): C col = q = r15.
// PV transposed: o' = mfma(V^T-frag, P-frag): C col = q = r15, rows = d.
// All softmax state (m, l, scl, inv) is lane-local. Defer-max THR=8 (log2 domain).
// KV tile 64, double-buffered LDS, granule-XOR swizzle via pre-swizzled global source.
__global__ __launch_bounds__(256, 4) void attn_mfma(
    const unsigned short* __restrict__ Q, const unsigned short* __restrict__ K,
    const unsigned short* __restrict__ VT, unsigned short* __restrict__ O)
{
    __shared__ __align__(16) unsigned short Ks[2][64][64];   // [kv][d] granule-swizzled (16K)
    __shared__ __align__(16) unsigned short Vs[2][64][64];   // [d][kv] granule-swizzled (16K)
    __shared__ __align__(16) unsigned short Ps[4][8][16][8]; // [wave][kg][q][e]  (8K)

    const int tid = threadIdx.x;
    const int l = tid & 63, w = tid >> 6;
    const int r15 = l & 15, g2 = l >> 4;          // g2 = 0..3
    const int qt = (blockIdx.x + blockIdx.y) & 31;   // decorrelate length from CU
    const int q0 = SEQ - 64 - qt * 64;
    const int q  = q0 + w * 16 + r15;             // this lane's q column
    const int bh = blockIdx.y;

    const unsigned short* Qb = Q + (size_t)bh * SEQ * HDIM;
    const unsigned short* Kb = K + (size_t)bh * SEQ * HDIM;
    const unsigned short* Vb = VT + (size_t)bh * HDIM * SEQ;

    // Q B-frag: lane holds Q[q][ks*32 + g2*8 .. +7]
    bfr8 qf[2];
    qf[0] = *(const bfr8*)(Qb + (size_t)q * HDIM + g2 * 8);
    qf[1] = *(const bfr8*)(Qb + (size_t)q * HDIM + 32 + g2 * 8);

    auto stage = [&](int buf, int kv0) {
        #pragma unroll
        for (int s = 0; s < 2; ++s) {
            int idx = s * 256 + tid;               // 512 granules each of K, V
            int row = idx >> 3, gs = idx & 7;
            gload16(Kb + (size_t)(kv0 + row) * HDIM + ((gs ^ (row & 7)) * 8), &Ks[buf][row][gs * 8]);
            gload16(Vb + (size_t)row * SEQ + kv0 + ((gs ^ (row & 7)) * 8), &Vs[buf][row][gs * 8]);
        }
    };

    f32x4 o[4] = {};                 // o[ch][i]: d = ch*16 + g2*4 + i, col q
    float m = -INFINITY, rden = 0.f;

    const int ntiles = q0 / 64 + 1;
    stage(0, 0);
    __syncthreads();

    for (int kt = 0; kt < ntiles; ++kt) {
        const int kv0 = kt * 64, buf = kt & 1;
        if (kt + 1 < ntiles) stage(buf ^ 1, kv0 + 64);

        // ---- S^T = K @ Q^T : s[c][i], kv = c*16 + g2*4 + i, q = col r15 ----
        f32x4 s[4];
        #pragma unroll
        for (int c = 0; c < 4; ++c) {
            const int rk = c * 16 + r15;
            const bfr8 kf0 = *(const bfr8*)&Ks[buf][rk][(g2 ^ (r15 & 7)) * 8];
            const bfr8 kf1 = *(const bfr8*)&Ks[buf][rk][((4 + g2) ^ (r15 & 7)) * 8];
            f32x4 z = {0.f, 0.f, 0.f, 0.f};
            z = __builtin_amdgcn_mfma_f32_16x16x32_bf16(kf0, qf[0], z, 0, 0, 0);
            s[c] = __builtin_amdgcn_mfma_f32_16x16x32_bf16(kf1, qf[1], z, 0, 0, 0);
        }

        if (kt == ntiles - 1) {      // causal mask: only the diagonal tile
            #pragma unroll
            for (int c = 0; c < 4; ++c)
                #pragma unroll
                for (int i = 0; i < 4; ++i)
                    if (kv0 + c * 16 + g2 * 4 + i > q) s[c][i] = -INFINITY;
        }

        // ---- lane-local online softmax with defer-max ----
        float tm = s[0][0];
        #pragma unroll
        for (int c = 0; c < 4; ++c)
            #pragma unroll
            for (int i = 0; i < 4; ++i) tm = fmaxf(tm, s[c][i]);
        tm = fmaxf(tm, __shfl_xor(tm, 16));
        tm = fmaxf(tm, __shfl_xor(tm, 32));
        if (__any(tm > m + 8.f)) {            // rescale (always taken on first tile)
            const float mn = fmaxf(m, tm);
            const float scl = exp2f(m - mn);  // 0 on first tile
            m = mn;
            rden *= scl;
            #pragma unroll
            for (int ch = 0; ch < 4; ++ch)
                #pragma unroll
                for (int i = 0; i < 4; ++i) o[ch][i] *= scl;
        }
        float ls = 0.f;
        #pragma unroll
        for (int c = 0; c < 4; ++c)
            #pragma unroll
            for (int i = 0; i < 4; ++i) {
                const float p = exp2f(s[c][i] - m);
                s[c][i] = p;
                ls += p;
            }
        ls += __shfl_xor(ls, 16);
        ls += __shfl_xor(ls, 32);
        rden += ls;

        // ---- P -> LDS in B-frag layout: Ps[kg][q][e] = P[kv=kg*8+e][q] ----
        {
            const int eb = (g2 & 1) * 4;
            #pragma unroll
            for (int c = 0; c < 4; ++c) {
                const int kg = c * 2 + (g2 >> 1);
                *(unsigned*)&Ps[w][kg][r15][eb]     = pack2bf(s[c][0], s[c][1]);
                *(unsigned*)&Ps[w][kg][r15][eb + 2] = pack2bf(s[c][2], s[c][3]);
            }
        }
        // wave-private buffer: within-wave lgkmcnt ordering suffices (no barrier)
        bfr8 pf[2];
        pf[0] = *(const bfr8*)&Ps[w][g2][r15][0];
        pf[1] = *(const bfr8*)&Ps[w][4 + g2][r15][0];

        // ---- O' += V^T @ P ----
        #pragma unroll
        for (int ch = 0; ch < 4; ++ch) {
            const int d = ch * 16 + r15;
            const bfr8 vf0 = *(const bfr8*)&Vs[buf][d][(g2 ^ (r15 & 7)) * 8];
            const bfr8 vf1 = *(const bfr8*)&Vs[buf][d][((4 + g2) ^ (r15 & 7)) * 8];
            o[ch] = __builtin_amdgcn_mfma_f32_16x16x32_bf16(vf0, pf[0], o[ch], 0, 0, 0);
            o[ch] = __builtin_amdgcn_mfma_f32_16x16x32_bf16(vf1, pf[1], o[ch], 0, 0, 0);
        }
        __syncthreads();   // protect K/V buffers (also drains staged loads)
    }

    const float inv = 1.f / rden;
    const int b = bh >> 4, h = bh & 15;
    unsigned short* Ob = O + ((size_t)b * SEQ + q) * DMODEL + h * HDIM + g2 * 4;
    #pragma unroll
    for (int ch = 0; ch < 4; ++ch) {
        uint2 pk;
        pk.x = pack2bf(o[ch][0] * inv, o[ch][1] * inv);
        pk.y = pack2bf(o[ch][2] * inv, o[ch][3] * inv);
        *(uint2*)(Ob + ch * 16) = pk;
    }
}

// ---------------- launch ----------------
extern "C" void kernel_launch(void* const* d_in, const int* in_sizes, int n_in,
                              void* d_out, int out_size, void* d_ws, size_t ws_size,
                              hipStream_t stream) {
    const float* x   = (const float*)d_in[0];
    const float* w_q = (const float*)d_in[1];
    const float* b_q = (const float*)d_in[2];
    const float* w_k = (const float*)d_in[3];
    const float* b_k = (const float*)d_in[4];
    const float* w_v = (const float*)d_in[5];
    const float* b_v = (const float*)d_in[6];
    const float* w_o = (const float*)d_in[7];
    const float* b_o = (const float*)d_in[8];
    float* out = (float*)d_out;

    const size_t NX = (size_t)MROWS * DMODEL;   // 4,194,304
    const size_t NW = (size_t)DMODEL * DMODEL;  // 1,048,576 = 2^20
    unsigned short* xb    = (unsigned short*)d_ws;
    unsigned short* wcomb = xb + NX;            // [3072][1024] = wq|wk|wv, then wo
    unsigned short* wob   = wcomb + 3 * NW;
    unsigned short* Qw    = wob + NW;           // [B,H,T,64] (scaled)
    unsigned short* Kw    = Qw + NX;            // [B,H,T,64]
    unsigned short* VTw   = Kw + NX;            // [B,H,64,T]
    unsigned short* Ow    = VTw + NX;           // [B,T,1024]

    cast_bf16<<<1024, 256, 0, stream>>>(x, xb, (int)NX);
    cast4_bf16<<<2048, 256, 0, stream>>>(w_q, w_k, w_v, w_o, wcomb);

    // fused QKV projection: [4096,1024] @ [3072,1024]^T
    gemm_bf16<128, 0><<<dim3(24, 32), 256, 0, stream>>>(xb, wcomb, b_q, b_k, b_v, Qw);

    attn_mfma<<<dim3(32, 32), 256, 0, stream>>>(Qw, Kw, VTw, Ow);

    // output projection: [4096,1024] @ [1024,1024]^T -> fp32
    gemm_bf16<64, 2><<<dim3(8, 64), 256, 0, stream>>>(Ow, wob, b_o, nullptr, nullptr, out);
}